// Round 1
// baseline (71.362 us; speedup 1.0000x reference)
//
#include <hip/hip_runtime.h>
#include <hip/hip_bf16.h>

#define N 1024
#define D 128
#define LEAK 0.2f

// workspace layout (float offsets)
#define OFF_WT      0
#define OFF_W1T     16384
#define OFF_W2T     32768
#define OFF_WPD     49152
#define OFF_WUT     49280
#define OFF_S1      49408
#define OFF_S2      50432
#define OFF_RMAX    51456
#define OFF_INVDEN  52480
#define OFF_WH      53504
#define OFF_BASE    184576
#define OFF_T       315648
#define OFF_TPART   446720

#define SPLIT 8     // j-range splits (cross-block partials)
#define ROWS 16     // i-rows per block in main kernel
#define JC 64       // j chunk staged in LDS

// ---------------------------------------------------------------------------
// 1. Transpose weights so GEMM B-reads coalesce; extract w_pd / w_ut columns.
__global__ void prep_kernel(const float* __restrict__ W, const float* __restrict__ W1,
                            const float* __restrict__ W2, float* __restrict__ Wt,
                            float* __restrict__ W1t, float* __restrict__ W2t,
                            float* __restrict__ wpd, float* __restrict__ wut) {
    int t = blockIdx.x * 256 + threadIdx.x;
    if (t >= D * D) return;
    int d = t >> 7, k = t & (D - 1);
    Wt[k * D + d]  = W[d * D + k];
    W1t[k * D + d] = W1[d * (D + 2) + k];
    W2t[k * D + d] = W2[d * D + k];
    if (k == 0) {
        wpd[d] = W1[d * (D + 2) + D];
        wut[d] = W1[d * (D + 2) + D + 1];
    }
}

// ---------------------------------------------------------------------------
// 2/4. out[i,d] = sum_k A[i,k] * Bt[k,d] (+ bias[d]).  block = 128 threads (d),
// RPB rows per block.
template <int RPB>
__global__ void gemm_kernel(const float* __restrict__ A, const float* __restrict__ Bt,
                            const float* __restrict__ bias, float* __restrict__ out) {
    __shared__ float arow[RPB][D];
    int d = threadIdx.x;
    int i0 = blockIdx.x * RPB;
    #pragma unroll
    for (int r = 0; r < RPB; r++) arow[r][d] = A[(i0 + r) * D + d];
    __syncthreads();
    float acc[RPB];
    float bs = bias ? bias[d] : 0.f;
    #pragma unroll
    for (int r = 0; r < RPB; r++) acc[r] = bs;
    #pragma unroll 4
    for (int k = 0; k < D; k++) {
        float bt = Bt[k * D + d];
        #pragma unroll
        for (int r = 0; r < RPB; r++) acc[r] = fmaf(arow[r][k], bt, acc[r]);
    }
    #pragma unroll
    for (int r = 0; r < RPB; r++) out[(i0 + r) * D + d] = acc[r];
}

// ---------------------------------------------------------------------------
// 3. s1[i] = Wh[i,:]·a[:D], s2[i] = Wh[i,:]·a[D:].  1 wave per row.
__global__ void row_dots_kernel(const float* __restrict__ Wh, const float* __restrict__ a,
                                float* __restrict__ s1, float* __restrict__ s2) {
    int i = blockIdx.x;
    int lane = threadIdx.x;   // 64
    float w0 = Wh[i * D + lane], w1 = Wh[i * D + 64 + lane];
    float p1 = w0 * a[lane] + w1 * a[64 + lane];
    float p2 = w0 * a[D + lane] + w1 * a[D + 64 + lane];
    #pragma unroll
    for (int off = 32; off > 0; off >>= 1) {
        p1 += __shfl_xor(p1, off);
        p2 += __shfl_xor(p2, off);
    }
    if (lane == 0) { s1[i] = p1; s2[i] = p2; }
}

// ---------------------------------------------------------------------------
// 5. Per-row softmax stats over masked leaky-relu scores.
//    exp(NEG - max) underflows to exactly 0 in f32, so only unmasked terms count.
__global__ void softmax_stats_kernel(const float* __restrict__ s1, const float* __restrict__ s2,
                                     const int* __restrict__ adj, float* __restrict__ rmax,
                                     float* __restrict__ invden) {
    int i = blockIdx.x;
    int t = threadIdx.x;  // 256
    float s1i = s1[i];
    float e[4]; int m[4];
    float mx = -3e38f;
    #pragma unroll
    for (int p = 0; p < 4; p++) {
        int j = t + p * 256;
        int av = adj[i * N + j];
        float x = s1i + s2[j];
        x = x > 0.f ? x : LEAK * x;
        e[p] = x; m[p] = av;
        if (av > 0) mx = fmaxf(mx, x);
    }
    #pragma unroll
    for (int off = 32; off > 0; off >>= 1) mx = fmaxf(mx, __shfl_xor(mx, off));
    __shared__ float redm[4], reds[4];
    int w = t >> 6, lane = t & 63;
    if (lane == 0) redm[w] = mx;
    __syncthreads();
    mx = fmaxf(fmaxf(redm[0], redm[1]), fmaxf(redm[2], redm[3]));
    float sum = 0.f;
    #pragma unroll
    for (int p = 0; p < 4; p++)
        if (m[p] > 0) sum += __expf(e[p] - mx);
    #pragma unroll
    for (int off = 32; off > 0; off >>= 1) sum += __shfl_xor(sum, off);
    if (lane == 0) reds[w] = sum;
    __syncthreads();
    if (t == 0) {
        float tot = reds[0] + reds[1] + reds[2] + reds[3];
        rmax[i] = mx;
        invden[i] = tot > 0.f ? 1.0f / tot : 0.f;
    }
}

// ---------------------------------------------------------------------------
// 6. Main fused kernel:
//    tpart[js][i][k] = sum_{j in js-slice} alpha[i,j] *
//                      relu(base[j,k] + pd[i,j]*wpd[k] + ut[i,j]*wut[k])
// block: 256 threads = (g=tid>>5 in 0..7 -> rows 2g,2g+1; kq=tid&31 -> k=4*kq..4*kq+3)
__global__ __launch_bounds__(256) void main_kernel(
    const float* __restrict__ base, const float* __restrict__ pd,
    const float* __restrict__ ut, const int* __restrict__ adj,
    const float* __restrict__ s1, const float* __restrict__ s2,
    const float* __restrict__ rmax, const float* __restrict__ invden,
    const float* __restrict__ wpd, const float* __restrict__ wut,
    float* __restrict__ tpart) {
    __shared__ float base_lds[JC][D];        // 32 KB
    __shared__ float sc[JC][ROWS][4];        // 16 KB: {pd, ut, alpha, pad}
    int ib = blockIdx.x & 63;                // N/ROWS = 64 i-tiles
    int js = blockIdx.x >> 6;                // 0..SPLIT-1
    int i0 = ib * ROWS;
    int tid = threadIdx.x;
    int kq = tid & 31, k0 = kq * 4;
    int g = tid >> 5;
    float4 wp = *(const float4*)&wpd[k0];
    float4 wu = *(const float4*)&wut[k0];
    float acc[2][4] = {};
    #pragma unroll
    for (int c = 0; c < N / SPLIT / JC; c++) {   // 2 chunks of 64 j
        int j0 = js * (N / SPLIT) + c * JC;
        __syncthreads();
        // stage base chunk (linear copy, coalesced)
        const float4* src = (const float4*)(base + j0 * D);
        float4* dst = (float4*)(&base_lds[0][0]);
        #pragma unroll
        for (int p = 0; p < 8; p++) dst[tid + p * 256] = src[tid + p * 256];
        // stage per-(i,j) scalars; alpha computed on the fly
        #pragma unroll
        for (int p = 0; p < 4; p++) {
            int idx = tid + p * 256;             // = r*64 + jj
            int r = idx >> 6, jj = idx & 63;
            int i = i0 + r, j = j0 + jj;
            float al = 0.f;
            if (adj[i * N + j] > 0) {
                float x = s1[i] + s2[j];
                x = x > 0.f ? x : LEAK * x;
                al = __expf(x - rmax[i]) * invden[i];
            }
            sc[jj][r][0] = pd[i * N + j];
            sc[jj][r][1] = ut[i * N + j];
            sc[jj][r][2] = al;
        }
        __syncthreads();
        #pragma unroll 2
        for (int jj = 0; jj < JC; jj++) {
            float4 b = *(const float4*)&base_lds[jj][k0];
            #pragma unroll
            for (int r = 0; r < 2; r++) {
                float4 s = *(const float4*)&sc[jj][2 * g + r][0];
                float v0 = fmaf(s.x, wp.x, b.x); v0 = fmaf(s.y, wu.x, v0); v0 = fmaxf(v0, 0.f);
                float v1 = fmaf(s.x, wp.y, b.y); v1 = fmaf(s.y, wu.y, v1); v1 = fmaxf(v1, 0.f);
                float v2 = fmaf(s.x, wp.z, b.z); v2 = fmaf(s.y, wu.z, v2); v2 = fmaxf(v2, 0.f);
                float v3 = fmaf(s.x, wp.w, b.w); v3 = fmaf(s.y, wu.w, v3); v3 = fmaxf(v3, 0.f);
                acc[r][0] = fmaf(s.z, v0, acc[r][0]);
                acc[r][1] = fmaf(s.z, v1, acc[r][1]);
                acc[r][2] = fmaf(s.z, v2, acc[r][2]);
                acc[r][3] = fmaf(s.z, v3, acc[r][3]);
            }
        }
    }
    #pragma unroll
    for (int r = 0; r < 2; r++) {
        int i = i0 + 2 * g + r;
        *(float4*)&tpart[(size_t)js * (N * D) + i * D + k0] = *(const float4*)&acc[r][0];
    }
}

// ---------------------------------------------------------------------------
// 7a. Sum the SPLIT j-partials.
__global__ void reduce_parts_kernel(const float* __restrict__ tpart, float* __restrict__ t) {
    int idx = blockIdx.x * 256 + threadIdx.x;  // N*D/256 = 512 blocks
    float v = 0.f;
    #pragma unroll
    for (int s = 0; s < SPLIT; s++) v += tpart[(size_t)s * (N * D) + idx];
    t[idx] = v;
}

// ---------------------------------------------------------------------------
// 7b. out[i,d] = sum_k t[i,k]*W2t[k,d] + b2[d] * (row had any neighbor ? 1 : 0)
template <int RPB>
__global__ void final_gemm_kernel(const float* __restrict__ t, const float* __restrict__ W2t,
                                  const float* __restrict__ b2, const float* __restrict__ invden,
                                  float* __restrict__ out) {
    __shared__ float arow[RPB][D];
    int d = threadIdx.x;
    int i0 = blockIdx.x * RPB;
    #pragma unroll
    for (int r = 0; r < RPB; r++) arow[r][d] = t[(i0 + r) * D + d];
    __syncthreads();
    float acc[RPB];
    float b2d = b2[d];
    #pragma unroll
    for (int r = 0; r < RPB; r++) acc[r] = (invden[i0 + r] > 0.f) ? b2d : 0.f;
    #pragma unroll 4
    for (int k = 0; k < D; k++) {
        float bt = W2t[k * D + d];
        #pragma unroll
        for (int r = 0; r < RPB; r++) acc[r] = fmaf(arow[r][k], bt, acc[r]);
    }
    #pragma unroll
    for (int r = 0; r < RPB; r++) out[(i0 + r) * D + d] = acc[r];
}

// ---------------------------------------------------------------------------
extern "C" void kernel_launch(void* const* d_in, const int* in_sizes, int n_in,
                              void* d_out, int out_size, void* d_ws, size_t ws_size,
                              hipStream_t stream) {
    (void)in_sizes; (void)n_in; (void)out_size; (void)ws_size;
    const float* h   = (const float*)d_in[0];
    const int*   adj = (const int*)d_in[1];
    const float* pd  = (const float*)d_in[2];
    const float* ut  = (const float*)d_in[3];
    const float* W   = (const float*)d_in[4];
    const float* a   = (const float*)d_in[5];
    const float* W1  = (const float*)d_in[6];
    const float* b1  = (const float*)d_in[7];
    const float* W2  = (const float*)d_in[8];
    const float* b2  = (const float*)d_in[9];
    float* out = (float*)d_out;
    float* ws = (float*)d_ws;

    float* Wt     = ws + OFF_WT;
    float* W1t    = ws + OFF_W1T;
    float* W2t    = ws + OFF_W2T;
    float* wpd    = ws + OFF_WPD;
    float* wut    = ws + OFF_WUT;
    float* s1     = ws + OFF_S1;
    float* s2     = ws + OFF_S2;
    float* rmax   = ws + OFF_RMAX;
    float* invden = ws + OFF_INVDEN;
    float* Wh     = ws + OFF_WH;
    float* baseb  = ws + OFF_BASE;
    float* tbuf   = ws + OFF_T;
    float* tpart  = ws + OFF_TPART;

    prep_kernel<<<64, 256, 0, stream>>>(W, W1, W2, Wt, W1t, W2t, wpd, wut);
    gemm_kernel<8><<<N / 8, 128, 0, stream>>>(h, Wt, nullptr, Wh);
    row_dots_kernel<<<N, 64, 0, stream>>>(Wh, a, s1, s2);
    gemm_kernel<8><<<N / 8, 128, 0, stream>>>(Wh, W1t, b1, baseb);
    softmax_stats_kernel<<<N, 256, 0, stream>>>(s1, s2, adj, rmax, invden);
    main_kernel<<<(N / ROWS) * SPLIT, 256, 0, stream>>>(baseb, pd, ut, adj, s1, s2,
                                                        rmax, invden, wpd, wut, tpart);
    reduce_parts_kernel<<<N * D / 256, 256, 0, stream>>>(tpart, tbuf);
    final_gemm_kernel<8><<<N / 8, 128, 0, stream>>>(tbuf, W2t, b2, invden, out);
}

// Round 3
// 57.196 us; speedup vs baseline: 1.2477x; 1.2477x over previous
//
#include <hip/hip_runtime.h>
#include <hip/hip_bf16.h>

#define N 1024
#define D 128
#define LEAK 0.2f

#define SPLIT 16    // j-range splits
#define IROWS 32    // i-rows per main block
#define JC 64       // j chunk per main block (= N/SPLIT)

// workspace layout (float offsets)
#define OFF_MT     0
#define OFF_W2T    16384
#define OFF_VA     32768
#define OFF_VB     32896
#define OFF_WPD    33024
#define OFF_WUT    33152
#define OFF_S1     33280
#define OFF_S2     34304
#define OFF_INVD   35328
#define OFF_BASE   36352
#define OFF_ALPHA  167424
#define OFF_TPART  1216000

// ---------------------------------------------------------------------------
// 1. prep: Mt = (W1h @ W)^T  (so base = h @ Mt row-major [k][d]),
//    W2t transpose, va = W^T a1, vb = W^T a2, wpd/wut columns of W1.
__global__ __launch_bounds__(256) void prep_kernel(
    const float* __restrict__ W, const float* __restrict__ W1,
    const float* __restrict__ W2, const float* __restrict__ a,
    float* __restrict__ Mt, float* __restrict__ W2t,
    float* __restrict__ va, float* __restrict__ vb,
    float* __restrict__ wpd, float* __restrict__ wut) {
    __shared__ float lds[128 * 129];   // ~64.5 KB, reused per-branch
    int b = blockIdx.x, tid = threadIdx.x;
    if (b < 64) {
        // Mt rows k0, k0+1:  Mt[k][d] = sum_q W1[d][q] * W[q][k]
        int k0 = 2 * b;
        int col = tid & 127, half = tid >> 7;
        #pragma unroll 8
        for (int p = 0; p < 64; p++) {
            int row = 2 * p + half;
            lds[row * 129 + col] = W1[row * (D + 2) + col];   // W1h part only
        }
        __syncthreads();
        int d = tid & 127, kl = tid >> 7;
        int k = k0 + kl;
        float acc = 0.f;
        #pragma unroll 8
        for (int q = 0; q < D; q++)
            acc = fmaf(lds[d * 129 + q], W[q * D + k], acc);
        Mt[k * D + d] = acc;            // lanes d-consecutive: coalesced
    } else if (b < 68) {
        // W2t 32-row tile:  W2t[k][d] = W2[d][k]
        int kbase = 32 * (b - 64);
        #pragma unroll
        for (int p = 0; p < 16; p++) {
            int idx = tid + p * 256;
            int rd = idx >> 5, cc = idx & 31;
            lds[cc * 129 + rd] = W2[rd * D + kbase + cc];
        }
        __syncthreads();
        #pragma unroll
        for (int p = 0; p < 16; p++) {
            int idx = tid + p * 256;
            int kl = idx >> 7, dd = idx & 127;
            W2t[(kbase + kl) * D + dd] = lds[kl * 129 + dd];
        }
    } else {
        if (tid < 128) {
            int k = tid;
            float a1 = 0.f, a2 = 0.f;
            #pragma unroll 8
            for (int q = 0; q < D; q++) {
                float w = W[q * D + k];
                a1 = fmaf(w, a[q], a1);
                a2 = fmaf(w, a[D + q], a2);
            }
            va[k] = a1; vb[k] = a2;
        } else {
            int d = tid - 128;
            wpd[d] = W1[d * (D + 2) + D];
            wut[d] = W1[d * (D + 2) + D + 1];
        }
    }
}

// ---------------------------------------------------------------------------
// 2. base[i][d] = b1[d] + sum_k h[i][k] Mt[k][d];  s1[i] = h[i]·va; s2[i] = h[i]·vb
//    s1/s2: 8 groups of 32 lanes, group g owns row g (FIX: was 4 waves / 8 rows).
__global__ __launch_bounds__(256) void base_kernel(
    const float* __restrict__ h, const float* __restrict__ Mt,
    const float* __restrict__ b1, const float* __restrict__ va,
    const float* __restrict__ vb, float* __restrict__ base,
    float* __restrict__ s1, float* __restrict__ s2) {
    __shared__ float hl[8][D];
    int tid = threadIdx.x;
    int i0 = blockIdx.x * 8;
    ((float4*)hl)[tid] = ((const float4*)(h + i0 * D))[tid];
    __syncthreads();
    // s1/s2: group of 32 lanes per row, 4 elems per lane
    {
        int g32 = tid >> 5, l32 = tid & 31;
        float p1 = 0.f, p2 = 0.f;
        #pragma unroll
        for (int q = 0; q < 4; q++) {
            float hv = hl[g32][l32 + 32 * q];
            p1 = fmaf(hv, va[l32 + 32 * q], p1);
            p2 = fmaf(hv, vb[l32 + 32 * q], p2);
        }
        #pragma unroll
        for (int off = 16; off > 0; off >>= 1) {
            p1 += __shfl_xor(p1, off);
            p2 += __shfl_xor(p2, off);
        }
        if (l32 == 0) { s1[i0 + g32] = p1; s2[i0 + g32] = p2; }
    }
    // GEMM: thread owns (row g, 4 d's)
    int g = tid >> 5, d0 = (tid & 31) * 4;
    float4 acc = *(const float4*)&b1[d0];
    #pragma unroll 8
    for (int k = 0; k < D; k++) {
        float4 m = *(const float4*)&Mt[k * D + d0];
        float hb = hl[g][k];
        acc.x = fmaf(hb, m.x, acc.x);
        acc.y = fmaf(hb, m.y, acc.y);
        acc.z = fmaf(hb, m.z, acc.z);
        acc.w = fmaf(hb, m.w, acc.w);
    }
    *(float4*)&base[(i0 + g) * D + d0] = acc;
}

// ---------------------------------------------------------------------------
// 3. alpha[i][j] materialized (masked softmax of leaky-relu scores); invden flag.
__global__ __launch_bounds__(256) void alpha_kernel(
    const float* __restrict__ s1, const float* __restrict__ s2,
    const int* __restrict__ adj, float* __restrict__ alpha,
    float* __restrict__ invden) {
    int i = blockIdx.x, tid = threadIdx.x;
    __shared__ float redm[4], reds[4];
    float s1i = s1[i];
    float e[4]; int m[4];
    float mx = -3e38f;
    #pragma unroll
    for (int p = 0; p < 4; p++) {
        int j = tid + p * 256;
        m[p] = adj[i * N + j];
        float x = s1i + s2[j];
        x = x > 0.f ? x : LEAK * x;
        e[p] = x;
        if (m[p] > 0) mx = fmaxf(mx, x);
    }
    #pragma unroll
    for (int off = 32; off > 0; off >>= 1) mx = fmaxf(mx, __shfl_xor(mx, off));
    int w = tid >> 6, l = tid & 63;
    if (l == 0) redm[w] = mx;
    __syncthreads();
    mx = fmaxf(fmaxf(redm[0], redm[1]), fmaxf(redm[2], redm[3]));
    float ev[4];
    float sum = 0.f;
    #pragma unroll
    for (int p = 0; p < 4; p++) {
        ev[p] = (m[p] > 0) ? __expf(e[p] - mx) : 0.f;
        sum += ev[p];
    }
    #pragma unroll
    for (int off = 32; off > 0; off >>= 1) sum += __shfl_xor(sum, off);
    if (l == 0) reds[w] = sum;
    __syncthreads();
    float tot = reds[0] + reds[1] + reds[2] + reds[3];
    float inv = tot > 0.f ? 1.0f / tot : 0.f;
    #pragma unroll
    for (int p = 0; p < 4; p++)
        alpha[i * N + tid + p * 256] = ev[p] * inv;
    if (tid == 0) invden[i] = inv;
}

// ---------------------------------------------------------------------------
// 4. main: tpart[js][i][k] = sum_{j in slice} alpha[i,j]*relu(base[j,k]+pd*wpd[k]+ut*wut[k])
//    256 thr: kq = tid&31 (4 k's), g = tid>>5 (4 rows each) -> 32 rows/block.
__global__ __launch_bounds__(256, 2) void main_kernel(
    const float* __restrict__ base, const float* __restrict__ alpha,
    const float* __restrict__ pd, const float* __restrict__ ut,
    const float* __restrict__ wpd, const float* __restrict__ wut,
    float* __restrict__ tpart) {
    __shared__ float bl[JC][D];          // 32 KB
    __shared__ float4 sc[IROWS][JC];     // 32 KB: {pd, ut, alpha, 0}
    int bid = blockIdx.x;
    int it = bid & 31, js = bid >> 5;
    int i0 = it * IROWS, j0 = js * JC;
    int tid = threadIdx.x;
    // stage base chunk (linear, coalesced, full-throughput b128 writes)
    #pragma unroll
    for (int p = 0; p < 8; p++)
        ((float4*)bl)[tid + p * 256] = ((const float4*)(base + j0 * D))[tid + p * 256];
    // stage per-(i,j) scalars as one float4 write each
    #pragma unroll
    for (int p = 0; p < 8; p++) {
        int idx = tid + p * 256;
        int r = idx >> 6, jj = idx & 63;
        int i = i0 + r, j = j0 + jj;
        sc[r][jj] = make_float4(pd[i * N + j], ut[i * N + j], alpha[i * N + j], 0.f);
    }
    __syncthreads();
    int kq = tid & 31, k0 = kq * 4, g = tid >> 5;
    float4 wp = *(const float4*)&wpd[k0];
    float4 wu = *(const float4*)&wut[k0];
    float acc[4][4] = {};
    #pragma unroll 2
    for (int jj = 0; jj < JC; jj++) {
        float4 b = *(const float4*)&bl[jj][k0];
        #pragma unroll
        for (int r = 0; r < 4; r++) {
            float4 s = sc[4 * g + r][jj];
            float v0 = fmaxf(fmaf(s.x, wp.x, fmaf(s.y, wu.x, b.x)), 0.f);
            float v1 = fmaxf(fmaf(s.x, wp.y, fmaf(s.y, wu.y, b.y)), 0.f);
            float v2 = fmaxf(fmaf(s.x, wp.z, fmaf(s.y, wu.z, b.z)), 0.f);
            float v3 = fmaxf(fmaf(s.x, wp.w, fmaf(s.y, wu.w, b.w)), 0.f);
            acc[r][0] = fmaf(s.z, v0, acc[r][0]);
            acc[r][1] = fmaf(s.z, v1, acc[r][1]);
            acc[r][2] = fmaf(s.z, v2, acc[r][2]);
            acc[r][3] = fmaf(s.z, v3, acc[r][3]);
        }
    }
    float* tp = tpart + (size_t)js * (N * D);
    #pragma unroll
    for (int r = 0; r < 4; r++) {
        int i = i0 + 4 * g + r;
        *(float4*)&tp[i * D + k0] = *(const float4*)&acc[r][0];
    }
}

// ---------------------------------------------------------------------------
// 5. final: out[i][d] = sum_k (sum_s tpart[s][i][k]) * W2t[k][d] + gated b2[d]
__global__ __launch_bounds__(128) void final_kernel(
    const float* __restrict__ tpart, const float* __restrict__ W2t,
    const float* __restrict__ b2, const float* __restrict__ invden,
    float* __restrict__ out) {
    __shared__ float arow[8][D];
    int d = threadIdx.x;
    int i0 = blockIdx.x * 8;
    #pragma unroll
    for (int r = 0; r < 8; r++) {
        float acc = 0.f;
        #pragma unroll
        for (int s = 0; s < SPLIT; s++)
            acc += tpart[(size_t)s * (N * D) + (i0 + r) * D + d];
        arow[r][d] = acc;
    }
    __syncthreads();
    float accs[8];
    float b2d = b2[d];
    #pragma unroll
    for (int r = 0; r < 8; r++) accs[r] = (invden[i0 + r] > 0.f) ? b2d : 0.f;
    #pragma unroll 4
    for (int k = 0; k < D; k++) {
        float w2 = W2t[k * D + d];
        #pragma unroll
        for (int r = 0; r < 8; r++) accs[r] = fmaf(arow[r][k], w2, accs[r]);
    }
    #pragma unroll
    for (int r = 0; r < 8; r++) out[(i0 + r) * D + d] = accs[r];
}

// ---------------------------------------------------------------------------
extern "C" void kernel_launch(void* const* d_in, const int* in_sizes, int n_in,
                              void* d_out, int out_size, void* d_ws, size_t ws_size,
                              hipStream_t stream) {
    (void)in_sizes; (void)n_in; (void)out_size; (void)ws_size;
    const float* h   = (const float*)d_in[0];
    const int*   adj = (const int*)d_in[1];
    const float* pd  = (const float*)d_in[2];
    const float* ut  = (const float*)d_in[3];
    const float* W   = (const float*)d_in[4];
    const float* a   = (const float*)d_in[5];
    const float* W1  = (const float*)d_in[6];
    const float* b1  = (const float*)d_in[7];
    const float* W2  = (const float*)d_in[8];
    const float* b2  = (const float*)d_in[9];
    float* out = (float*)d_out;
    float* ws = (float*)d_ws;

    float* Mt     = ws + OFF_MT;
    float* W2t    = ws + OFF_W2T;
    float* va     = ws + OFF_VA;
    float* vb     = ws + OFF_VB;
    float* wpd    = ws + OFF_WPD;
    float* wut    = ws + OFF_WUT;
    float* s1     = ws + OFF_S1;
    float* s2     = ws + OFF_S2;
    float* invden = ws + OFF_INVD;
    float* baseb  = ws + OFF_BASE;
    float* alphab = ws + OFF_ALPHA;
    float* tpart  = ws + OFF_TPART;

    prep_kernel<<<69, 256, 0, stream>>>(W, W1, W2, a, Mt, W2t, va, vb, wpd, wut);
    base_kernel<<<N / 8, 256, 0, stream>>>(h, Mt, b1, va, vb, baseb, s1, s2);
    alpha_kernel<<<N, 256, 0, stream>>>(s1, s2, adj, alphab, invden);
    main_kernel<<<(N / IROWS) * SPLIT, 256, 0, stream>>>(baseb, alphab, pd, ut, wpd, wut, tpart);
    final_kernel<<<N / 8, 128, 0, stream>>>(tpart, W2t, b2, invden, out);
}

// Round 4
// 52.874 us; speedup vs baseline: 1.3497x; 1.0817x over previous
//
#include <hip/hip_runtime.h>
#include <hip/hip_bf16.h>

#define N 1024
#define D 128
#define LEAK 0.2f

#define SPLIT 32    // j-range splits (= number of tpart slices)
#define IROWS 64    // i-rows per main block
#define JC 32       // j chunk per main block (= N/SPLIT)

// workspace layout (float offsets)
#define OFF_MT     0
#define OFF_W2T    16384
#define OFF_WPD    32768
#define OFF_WUT    33024
#define OFF_S1     33280
#define OFF_S2     34304
#define OFF_INVD   35328
#define OFF_BASE   36864
#define OFF_ALPHA  167936
#define OFF_TPART  1216512

// ---------------------------------------------------------------------------
// K1: heterogeneous prep.
//   b 0..63   : Mt rows 2b,2b+1   (Mt = (W1h @ W)^T, so base = h @ Mt)
//   b 64..67  : W2t 32-row tile   (W2t[k][d] = W2[d][k])
//   b 68      : wpd/wut extraction
//   b 69..196 : s1/s2 for rows (b-69)*8.. (recomputes va=W^T a1, vb=W^T a2 per block)
__global__ __launch_bounds__(256) void prep_kernel(
    const float* __restrict__ W, const float* __restrict__ W1,
    const float* __restrict__ W2, const float* __restrict__ a,
    const float* __restrict__ h,
    float* __restrict__ Mt, float* __restrict__ W2t,
    float* __restrict__ wpd, float* __restrict__ wut,
    float* __restrict__ s1, float* __restrict__ s2) {
    __shared__ float lds[128 * 129];   // 64.5 KB, reused per-branch
    int b = blockIdx.x, tid = threadIdx.x;
    if (b < 64) {
        // Mt rows k0, k0+1:  Mt[k][d] = sum_q W1[d][q] * W[q][k]
        int k0 = 2 * b;
        int col = tid & 127, half = tid >> 7;
        #pragma unroll 8
        for (int p = 0; p < 64; p++) {
            int row = 2 * p + half;
            lds[row * 129 + col] = W1[row * (D + 2) + col];   // W1h part only
        }
        __syncthreads();
        int d = tid & 127, kl = tid >> 7;
        int k = k0 + kl;
        float acc = 0.f;
        #pragma unroll 8
        for (int q = 0; q < D; q++)
            acc = fmaf(lds[d * 129 + q], W[q * D + k], acc);
        Mt[k * D + d] = acc;
    } else if (b < 68) {
        int kbase = 32 * (b - 64);
        #pragma unroll
        for (int p = 0; p < 16; p++) {
            int idx = tid + p * 256;
            int rd = idx >> 5, cc = idx & 31;
            lds[cc * 129 + rd] = W2[rd * D + kbase + cc];
        }
        __syncthreads();
        #pragma unroll
        for (int p = 0; p < 16; p++) {
            int idx = tid + p * 256;
            int kl = idx >> 7, dd = idx & 127;
            W2t[(kbase + kl) * D + dd] = lds[kl * 129 + dd];
        }
    } else if (b == 68) {
        if (tid < 128) wpd[tid] = W1[tid * (D + 2) + D];
        else           wut[tid - 128] = W1[(tid - 128) * (D + 2) + D + 1];
    } else {
        // s1/s2 for 8 rows; va/vb recomputed locally (cheap, W is L2-resident)
        float* vab = lds;            // [2][128]
        float* hls = lds + 256;      // [8][128]
        int i0 = (b - 69) * 8;
        {
            int half = tid >> 7, k = tid & 127;
            const float* av = a + half * D;
            float acc = 0.f;
            #pragma unroll 8
            for (int q = 0; q < D; q++)
                acc = fmaf(W[q * D + k], av[q], acc);
            vab[half * D + k] = acc;
        }
        ((float4*)hls)[tid] = ((const float4*)(h + i0 * D))[tid];
        __syncthreads();
        int g32 = tid >> 5, l32 = tid & 31;
        float p1 = 0.f, p2 = 0.f;
        #pragma unroll
        for (int q = 0; q < 4; q++) {
            float hv = hls[g32 * D + l32 + 32 * q];
            p1 = fmaf(hv, vab[l32 + 32 * q], p1);
            p2 = fmaf(hv, vab[D + l32 + 32 * q], p2);
        }
        #pragma unroll
        for (int off = 16; off > 0; off >>= 1) {
            p1 += __shfl_xor(p1, off);
            p2 += __shfl_xor(p2, off);
        }
        if (l32 == 0) { s1[i0 + g32] = p1; s2[i0 + g32] = p2; }
    }
}

// ---------------------------------------------------------------------------
// K2: heterogeneous.
//   b 0..127   : base[i][d] = b1[d] + sum_k h[i][k] Mt[k][d]  (8 rows/block)
//   b 128..383 : alpha rows (softmax, wave-per-row, 4 rows/block)
__global__ __launch_bounds__(256) void base_alpha_kernel(
    const float* __restrict__ h, const float* __restrict__ Mt,
    const float* __restrict__ b1, const int* __restrict__ adj,
    const float* __restrict__ s1, const float* __restrict__ s2,
    float* __restrict__ base, float* __restrict__ alpha,
    float* __restrict__ invden) {
    int b = blockIdx.x, tid = threadIdx.x;
    if (b < 128) {
        __shared__ float hl[8][D];
        int i0 = b * 8;
        ((float4*)hl)[tid] = ((const float4*)(h + i0 * D))[tid];
        __syncthreads();
        int g = tid >> 5, d0 = (tid & 31) * 4;
        float4 acc = *(const float4*)&b1[d0];
        #pragma unroll 8
        for (int k = 0; k < D; k++) {
            float4 m = *(const float4*)&Mt[k * D + d0];
            float hb = hl[g][k];
            acc.x = fmaf(hb, m.x, acc.x);
            acc.y = fmaf(hb, m.y, acc.y);
            acc.z = fmaf(hb, m.z, acc.z);
            acc.w = fmaf(hb, m.w, acc.w);
        }
        *(float4*)&base[(i0 + g) * D + d0] = acc;
    } else {
        // wave w owns row i0+w; lane handles 16 j's
        int w = tid >> 6, l = tid & 63;
        int i = (b - 128) * 4 + w;
        float s1i = s1[i];
        float e[16]; int m[16];
        float mx = -3e38f;
        #pragma unroll
        for (int p = 0; p < 16; p++) {
            int j = l + 64 * p;
            m[p] = adj[i * N + j];
            float x = s1i + s2[j];
            x = x > 0.f ? x : LEAK * x;
            e[p] = x;
            if (m[p] > 0) mx = fmaxf(mx, x);
        }
        #pragma unroll
        for (int off = 32; off > 0; off >>= 1) mx = fmaxf(mx, __shfl_xor(mx, off));
        float sum = 0.f;
        float ev[16];
        #pragma unroll
        for (int p = 0; p < 16; p++) {
            ev[p] = (m[p] > 0) ? __expf(e[p] - mx) : 0.f;
            sum += ev[p];
        }
        #pragma unroll
        for (int off = 32; off > 0; off >>= 1) sum += __shfl_xor(sum, off);
        float inv = sum > 0.f ? 1.0f / sum : 0.f;
        #pragma unroll
        for (int p = 0; p < 16; p++)
            alpha[i * N + l + 64 * p] = ev[p] * inv;
        if (l == 0) invden[i] = inv;
    }
}

// ---------------------------------------------------------------------------
// K3: main.  tpart[js][i][k] = sum_{j in slice} alpha[i,j]*relu(base[j,k]+pd*wpd[k]+ut*wut[k])
// 256 thr: kq = tid&15 -> k in {4kq..4kq+3} u {64+4kq..}, g = tid>>4 -> rows 4g..4g+3.
// 64 rows x 32 j per block; LDS ~50 KB -> 3 blocks/CU.
__global__ __launch_bounds__(256, 3) void main_kernel(
    const float* __restrict__ base, const float* __restrict__ alpha,
    const float* __restrict__ pd, const float* __restrict__ ut,
    const float* __restrict__ wpd, const float* __restrict__ wut,
    float* __restrict__ tpart) {
    __shared__ float bl[JC][D];            // 16 KB
    __shared__ float4 sc[IROWS][JC + 1];   // 33.8 KB (padded: conflict-free group reads)
    int bid = blockIdx.x;
    int it = bid & 15, js = bid >> 4;
    int i0 = it * IROWS, j0 = js * JC;
    int tid = threadIdx.x;
    // stage base chunk (linear, coalesced)
    #pragma unroll
    for (int p = 0; p < 4; p++)
        ((float4*)bl)[tid + p * 256] = ((const float4*)(base + j0 * D))[tid + p * 256];
    // stage per-(i,j) scalars {pd, ut, alpha, 0}
    #pragma unroll
    for (int p = 0; p < 8; p++) {
        int idx = tid + p * 256;
        int r = idx >> 5, jj = idx & 31;
        int i = i0 + r, j = j0 + jj;
        sc[r][jj] = make_float4(pd[i * N + j], ut[i * N + j], alpha[i * N + j], 0.f);
    }
    __syncthreads();
    int kq = tid & 15, k0 = kq * 4, g = tid >> 4;
    float4 wp0 = *(const float4*)&wpd[k0];
    float4 wp1 = *(const float4*)&wpd[k0 + 64];
    float4 wu0 = *(const float4*)&wut[k0];
    float4 wu1 = *(const float4*)&wut[k0 + 64];
    float4 acc0[4] = {}, acc1[4] = {};
    #pragma unroll 2
    for (int jj = 0; jj < JC; jj++) {
        float4 b0 = *(const float4*)&bl[jj][k0];
        float4 b1v = *(const float4*)&bl[jj][k0 + 64];
        #pragma unroll
        for (int r = 0; r < 4; r++) {
            float4 s = sc[4 * g + r][jj];
            float v;
            v = fmaxf(fmaf(s.x, wp0.x, fmaf(s.y, wu0.x, b0.x)), 0.f); acc0[r].x = fmaf(s.z, v, acc0[r].x);
            v = fmaxf(fmaf(s.x, wp0.y, fmaf(s.y, wu0.y, b0.y)), 0.f); acc0[r].y = fmaf(s.z, v, acc0[r].y);
            v = fmaxf(fmaf(s.x, wp0.z, fmaf(s.y, wu0.z, b0.z)), 0.f); acc0[r].z = fmaf(s.z, v, acc0[r].z);
            v = fmaxf(fmaf(s.x, wp0.w, fmaf(s.y, wu0.w, b0.w)), 0.f); acc0[r].w = fmaf(s.z, v, acc0[r].w);
            v = fmaxf(fmaf(s.x, wp1.x, fmaf(s.y, wu1.x, b1v.x)), 0.f); acc1[r].x = fmaf(s.z, v, acc1[r].x);
            v = fmaxf(fmaf(s.x, wp1.y, fmaf(s.y, wu1.y, b1v.y)), 0.f); acc1[r].y = fmaf(s.z, v, acc1[r].y);
            v = fmaxf(fmaf(s.x, wp1.z, fmaf(s.y, wu1.z, b1v.z)), 0.f); acc1[r].z = fmaf(s.z, v, acc1[r].z);
            v = fmaxf(fmaf(s.x, wp1.w, fmaf(s.y, wu1.w, b1v.w)), 0.f); acc1[r].w = fmaf(s.z, v, acc1[r].w);
        }
    }
    float* tp = tpart + (size_t)js * (N * D);
    #pragma unroll
    for (int r = 0; r < 4; r++) {
        int i = i0 + 4 * g + r;
        *(float4*)&tp[i * D + k0]      = acc0[r];
        *(float4*)&tp[i * D + k0 + 64] = acc1[r];
    }
}

// ---------------------------------------------------------------------------
// K4: reduce SPLIT partials + final GEMM.  256 blocks x 4 rows.
__global__ __launch_bounds__(256) void final_kernel(
    const float* __restrict__ tpart, const float* __restrict__ W2t,
    const float* __restrict__ b2, const float* __restrict__ invden,
    float* __restrict__ out) {
    __shared__ float tl[4][D];
    int i0 = blockIdx.x * 4;
    int tid = threadIdx.x;
    int d = tid & 127, rh = tid >> 7;     // rh 0/1 -> rows rh*2, rh*2+1
    #pragma unroll
    for (int r2 = 0; r2 < 2; r2++) {
        int row = rh * 2 + r2;
        float v = 0.f;
        #pragma unroll
        for (int s = 0; s < SPLIT; s++)
            v += tpart[((size_t)s * N + (i0 + row)) * D + d];
        tl[row][d] = v;
    }
    __syncthreads();
    float b2d = b2[d];
    float acc[2];
    #pragma unroll
    for (int r2 = 0; r2 < 2; r2++)
        acc[r2] = (invden[i0 + rh * 2 + r2] > 0.f) ? b2d : 0.f;
    #pragma unroll 4
    for (int k = 0; k < D; k++) {
        float w2 = W2t[k * D + d];
        #pragma unroll
        for (int r2 = 0; r2 < 2; r2++)
            acc[r2] = fmaf(tl[rh * 2 + r2][k], w2, acc[r2]);
    }
    #pragma unroll
    for (int r2 = 0; r2 < 2; r2++)
        out[(i0 + rh * 2 + r2) * D + d] = acc[r2];
}

// ---------------------------------------------------------------------------
extern "C" void kernel_launch(void* const* d_in, const int* in_sizes, int n_in,
                              void* d_out, int out_size, void* d_ws, size_t ws_size,
                              hipStream_t stream) {
    (void)in_sizes; (void)n_in; (void)out_size; (void)ws_size;
    const float* h   = (const float*)d_in[0];
    const int*   adj = (const int*)d_in[1];
    const float* pd  = (const float*)d_in[2];
    const float* ut  = (const float*)d_in[3];
    const float* W   = (const float*)d_in[4];
    const float* a   = (const float*)d_in[5];
    const float* W1  = (const float*)d_in[6];
    const float* b1  = (const float*)d_in[7];
    const float* W2  = (const float*)d_in[8];
    const float* b2  = (const float*)d_in[9];
    float* out = (float*)d_out;
    float* ws = (float*)d_ws;

    float* Mt     = ws + OFF_MT;
    float* W2t    = ws + OFF_W2T;
    float* wpd    = ws + OFF_WPD;
    float* wut    = ws + OFF_WUT;
    float* s1     = ws + OFF_S1;
    float* s2     = ws + OFF_S2;
    float* invden = ws + OFF_INVD;
    float* baseb  = ws + OFF_BASE;
    float* alphab = ws + OFF_ALPHA;
    float* tpart  = ws + OFF_TPART;

    prep_kernel<<<197, 256, 0, stream>>>(W, W1, W2, a, h, Mt, W2t, wpd, wut, s1, s2);
    base_alpha_kernel<<<384, 256, 0, stream>>>(h, Mt, b1, adj, s1, s2, baseb, alphab, invden);
    main_kernel<<<(N / IROWS) * SPLIT, 256, 0, stream>>>(baseb, alphab, pd, ut, wpd, wut, tpart);
    final_kernel<<<N / 4, 256, 0, stream>>>(tpart, W2t, b2, invden, out);
}

// Round 5
// 48.311 us; speedup vs baseline: 1.4771x; 1.0944x over previous
//
#include <hip/hip_runtime.h>
#include <hip/hip_bf16.h>

#define N 1024
#define D 128
#define LEAK 0.2f

#define MROWS 4          // i-rows per mega block
#define MJC 64           // j chunk
#define NCHUNK (N / MJC) // 16

// workspace layout (float offsets)
#define OFF_MT   0
#define OFF_W2T  16384
#define OFF_WPD  32768
#define OFF_WUT  32896
#define OFF_S1   33024
#define OFF_S2   34048
#define OFF_BASE 35072

// ---------------------------------------------------------------------------
// K1: heterogeneous prep.
//   b 0..63   : Mt rows 2b,2b+1   (Mt = (W1h @ W)^T, so base = h @ Mt)
//   b 64..67  : W2t 32-row tile   (W2t[k][d] = W2[d][k])
//   b 68      : wpd/wut extraction
//   b 69..196 : s1/s2 for rows (b-69)*8.. (recomputes va=W^T a1, vb=W^T a2)
__global__ __launch_bounds__(256) void prep_kernel(
    const float* __restrict__ W, const float* __restrict__ W1,
    const float* __restrict__ W2, const float* __restrict__ a,
    const float* __restrict__ h,
    float* __restrict__ Mt, float* __restrict__ W2t,
    float* __restrict__ wpd, float* __restrict__ wut,
    float* __restrict__ s1, float* __restrict__ s2) {
    __shared__ float lds[128 * 129];
    int b = blockIdx.x, tid = threadIdx.x;
    if (b < 64) {
        int k0 = 2 * b;
        int col = tid & 127, half = tid >> 7;
        #pragma unroll 8
        for (int p = 0; p < 64; p++) {
            int row = 2 * p + half;
            lds[row * 129 + col] = W1[row * (D + 2) + col];
        }
        __syncthreads();
        int d = tid & 127, kl = tid >> 7;
        int k = k0 + kl;
        float acc = 0.f;
        #pragma unroll 8
        for (int q = 0; q < D; q++)
            acc = fmaf(lds[d * 129 + q], W[q * D + k], acc);
        Mt[k * D + d] = acc;
    } else if (b < 68) {
        int kbase = 32 * (b - 64);
        #pragma unroll
        for (int p = 0; p < 16; p++) {
            int idx = tid + p * 256;
            int rd = idx >> 5, cc = idx & 31;
            lds[cc * 129 + rd] = W2[rd * D + kbase + cc];
        }
        __syncthreads();
        #pragma unroll
        for (int p = 0; p < 16; p++) {
            int idx = tid + p * 256;
            int kl = idx >> 7, dd = idx & 127;
            W2t[(kbase + kl) * D + dd] = lds[kl * 129 + dd];
        }
    } else if (b == 68) {
        if (tid < 128) wpd[tid] = W1[tid * (D + 2) + D];
        else           wut[tid - 128] = W1[(tid - 128) * (D + 2) + D + 1];
    } else {
        float* vab = lds;            // [2][128]
        float* hls = lds + 256;      // [8][128]
        int i0 = (b - 69) * 8;
        {
            int half = tid >> 7, k = tid & 127;
            const float* av = a + half * D;
            float acc = 0.f;
            #pragma unroll 8
            for (int q = 0; q < D; q++)
                acc = fmaf(W[q * D + k], av[q], acc);
            vab[half * D + k] = acc;
        }
        ((float4*)hls)[tid] = ((const float4*)(h + i0 * D))[tid];
        __syncthreads();
        int g32 = tid >> 5, l32 = tid & 31;
        float p1 = 0.f, p2 = 0.f;
        #pragma unroll
        for (int q = 0; q < 4; q++) {
            float hv = hls[g32 * D + l32 + 32 * q];
            p1 = fmaf(hv, vab[l32 + 32 * q], p1);
            p2 = fmaf(hv, vab[D + l32 + 32 * q], p2);
        }
        #pragma unroll
        for (int off = 16; off > 0; off >>= 1) {
            p1 += __shfl_xor(p1, off);
            p2 += __shfl_xor(p2, off);
        }
        if (l32 == 0) { s1[i0 + g32] = p1; s2[i0 + g32] = p2; }
    }
}

// ---------------------------------------------------------------------------
// K2: base[i][d] = b1[d] + sum_k h[i][k] Mt[k][d]   (8 rows/block, 128 blocks)
__global__ __launch_bounds__(256) void base_kernel(
    const float* __restrict__ h, const float* __restrict__ Mt,
    const float* __restrict__ b1, float* __restrict__ base) {
    __shared__ float hl[8][D];
    int tid = threadIdx.x;
    int i0 = blockIdx.x * 8;
    ((float4*)hl)[tid] = ((const float4*)(h + i0 * D))[tid];
    __syncthreads();
    int g = tid >> 5, d0 = (tid & 31) * 4;
    float4 acc = *(const float4*)&b1[d0];
    #pragma unroll 8
    for (int k = 0; k < D; k++) {
        float4 m = *(const float4*)&Mt[k * D + d0];
        float hb = hl[g][k];
        acc.x = fmaf(hb, m.x, acc.x);
        acc.y = fmaf(hb, m.y, acc.y);
        acc.z = fmaf(hb, m.z, acc.z);
        acc.w = fmaf(hb, m.w, acc.w);
    }
    *(float4*)&base[(i0 + g) * D + d0] = acc;
}

// ---------------------------------------------------------------------------
// K3: mega.  256 blocks x 512 thr; block owns rows i0..i0+3.
//   phase 0: alpha for 4 rows -> LDS (16KB); gate sums.
//   main:    16 double-buffered chunks of 64 j; R=4 rows/thread, 8 k/thread.
//   final:   cross-group reduce + t @ W2t + gated b2 -> out.
__global__ __launch_bounds__(512, 1) void mega_kernel(
    const float* __restrict__ base, const float* __restrict__ s1,
    const float* __restrict__ s2, const int* __restrict__ adj,
    const float* __restrict__ pd, const float* __restrict__ ut,
    const float* __restrict__ wpd, const float* __restrict__ wut,
    const float* __restrict__ W2t, const float* __restrict__ b2,
    float* __restrict__ out) {
    __shared__ float pool[16384];          // 64KB: bl[2][64][128] | racc[32][4][128]
    __shared__ float al[MROWS][N];         // 16KB alpha
    __shared__ float4 sc[2][MROWS][MJC];   // 4KB {pd, ut, alpha, 0}
    __shared__ float red[8], red2[8], gsum[MROWS];
    __shared__ float tl[MROWS][D];

    float (*bl)[MJC][D]   = (float (*)[MJC][D])pool;
    float (*racc)[MROWS][D] = (float (*)[MROWS][D])pool;

    const int tid = threadIdx.x;
    const int i0 = blockIdx.x * MROWS;

    // ---- issue chunk-0 staging loads early (hide HBM under alpha phase) ----
    float4 pre0, pre1, pre2, pre3;
    float ppd = 0.f, put = 0.f;
    {
        const float4* src = (const float4*)base;     // chunk 0: j0 = 0
        pre0 = src[tid];        pre1 = src[tid + 512];
        pre2 = src[tid + 1024]; pre3 = src[tid + 1536];
        if (tid < 256) {
            int rr = tid >> 6, jj = tid & 63;
            ppd = pd[(i0 + rr) * N + jj];
            put = ut[(i0 + rr) * N + jj];
        }
    }

    // ---- phase 0: alpha (row r <-> threads [128r,128r+128) = waves 2r,2r+1) ----
    {
        int r = tid >> 7;
        int i = i0 + r;
        int jb = (tid & 127) * 8;
        float s1i = s1[i];
        float4 sa = *(const float4*)&s2[jb];
        float4 sb = *(const float4*)&s2[jb + 4];
        int4 ma = *(const int4*)&adj[i * N + jb];
        int4 mb = *(const int4*)&adj[i * N + jb + 4];
        float e[8]; int mm[8];
        e[0]=s1i+sa.x; e[1]=s1i+sa.y; e[2]=s1i+sa.z; e[3]=s1i+sa.w;
        e[4]=s1i+sb.x; e[5]=s1i+sb.y; e[6]=s1i+sb.z; e[7]=s1i+sb.w;
        mm[0]=ma.x; mm[1]=ma.y; mm[2]=ma.z; mm[3]=ma.w;
        mm[4]=mb.x; mm[5]=mb.y; mm[6]=mb.z; mm[7]=mb.w;
        float mx = -3e38f;
        #pragma unroll
        for (int q = 0; q < 8; q++) {
            e[q] = e[q] > 0.f ? e[q] : LEAK * e[q];
            if (mm[q] > 0) mx = fmaxf(mx, e[q]);
        }
        #pragma unroll
        for (int off = 32; off > 0; off >>= 1) mx = fmaxf(mx, __shfl_xor(mx, off));
        int wid = tid >> 6, lane = tid & 63;
        if (lane == 0) red[wid] = mx;
        __syncthreads();
        mx = fmaxf(red[2 * r], red[2 * r + 1]);
        float ev[8]; float sum = 0.f;
        #pragma unroll
        for (int q = 0; q < 8; q++) {
            ev[q] = (mm[q] > 0) ? __expf(e[q] - mx) : 0.f;
            sum += ev[q];
        }
        #pragma unroll
        for (int off = 32; off > 0; off >>= 1) sum += __shfl_xor(sum, off);
        if (lane == 0) red2[wid] = sum;
        __syncthreads();
        sum = red2[2 * r] + red2[2 * r + 1];
        float inv = sum > 0.f ? 1.f / sum : 0.f;
        *(float4*)&al[r][jb]     = make_float4(ev[0]*inv, ev[1]*inv, ev[2]*inv, ev[3]*inv);
        *(float4*)&al[r][jb + 4] = make_float4(ev[4]*inv, ev[5]*inv, ev[6]*inv, ev[7]*inv);
        if ((tid & 127) == 0) gsum[r] = sum;
    }
    __syncthreads();   // al + gsum visible

    // ---- commit chunk 0 ----
    {
        float4* dst = (float4*)bl[0];
        dst[tid] = pre0; dst[tid + 512] = pre1;
        dst[tid + 1024] = pre2; dst[tid + 1536] = pre3;
        if (tid < 256) {
            int rr = tid >> 6, jj = tid & 63;
            sc[0][rr][jj] = make_float4(ppd, put, al[rr][jj], 0.f);
        }
    }
    __syncthreads();

    const int l16 = tid & 15, g = tid >> 4;       // 32 groups x 16 lanes
    const int k0a = l16 * 4, k0b = 64 + l16 * 4;  // split-k: 8 k's per lane
    const float4 wp0 = *(const float4*)&wpd[k0a];
    const float4 wp1 = *(const float4*)&wpd[k0b];
    const float4 wu0 = *(const float4*)&wut[k0a];
    const float4 wu1 = *(const float4*)&wut[k0b];

    float4 a0[MROWS] = {}, a1[MROWS] = {};

    for (int c = 0; c < NCHUNK; c++) {
        int cb = c & 1;
        // issue next-chunk staging (overlaps compute below)
        if (c + 1 < NCHUNK) {
            const float4* src = (const float4*)(base + (c + 1) * MJC * D);
            pre0 = src[tid];        pre1 = src[tid + 512];
            pre2 = src[tid + 1024]; pre3 = src[tid + 1536];
            if (tid < 256) {
                int rr = tid >> 6, jj = tid & 63;
                ppd = pd[(i0 + rr) * N + (c + 1) * MJC + jj];
                put = ut[(i0 + rr) * N + (c + 1) * MJC + jj];
            }
        }
        // compute chunk c: group g owns j-locals {2g, 2g+1}
        #pragma unroll
        for (int jj2 = 0; jj2 < 2; jj2++) {
            int jl = g * 2 + jj2;
            float4 b0  = *(const float4*)&bl[cb][jl][k0a];
            float4 b1v = *(const float4*)&bl[cb][jl][k0b];
            #pragma unroll
            for (int r = 0; r < MROWS; r++) {
                float4 s = sc[cb][r][jl];
                float v;
                v = fmaxf(fmaf(s.x, wp0.x, fmaf(s.y, wu0.x, b0.x)), 0.f);  a0[r].x = fmaf(s.z, v, a0[r].x);
                v = fmaxf(fmaf(s.x, wp0.y, fmaf(s.y, wu0.y, b0.y)), 0.f);  a0[r].y = fmaf(s.z, v, a0[r].y);
                v = fmaxf(fmaf(s.x, wp0.z, fmaf(s.y, wu0.z, b0.z)), 0.f);  a0[r].z = fmaf(s.z, v, a0[r].z);
                v = fmaxf(fmaf(s.x, wp0.w, fmaf(s.y, wu0.w, b0.w)), 0.f);  a0[r].w = fmaf(s.z, v, a0[r].w);
                v = fmaxf(fmaf(s.x, wp1.x, fmaf(s.y, wu1.x, b1v.x)), 0.f); a1[r].x = fmaf(s.z, v, a1[r].x);
                v = fmaxf(fmaf(s.x, wp1.y, fmaf(s.y, wu1.y, b1v.y)), 0.f); a1[r].y = fmaf(s.z, v, a1[r].y);
                v = fmaxf(fmaf(s.x, wp1.z, fmaf(s.y, wu1.z, b1v.z)), 0.f); a1[r].z = fmaf(s.z, v, a1[r].z);
                v = fmaxf(fmaf(s.x, wp1.w, fmaf(s.y, wu1.w, b1v.w)), 0.f); a1[r].w = fmaf(s.z, v, a1[r].w);
            }
        }
        // commit next chunk into the other buffer (race-free: dbuf)
        if (c + 1 < NCHUNK) {
            int nb = (c + 1) & 1;
            float4* dst = (float4*)bl[nb];
            dst[tid] = pre0; dst[tid + 512] = pre1;
            dst[tid + 1024] = pre2; dst[tid + 1536] = pre3;
            if (tid < 256) {
                int rr = tid >> 6, jj = tid & 63;
                sc[nb][rr][jj] = make_float4(ppd, put, al[rr][(c + 1) * MJC + jj], 0.f);
            }
        }
        __syncthreads();
    }

    // ---- cross-group reduce (racc overlays bl; all compute done) ----
    #pragma unroll
    for (int r = 0; r < MROWS; r++) {
        *(float4*)&racc[g][r][k0a] = a0[r];
        *(float4*)&racc[g][r][k0b] = a1[r];
    }
    __syncthreads();
    {
        int rr = tid >> 7, k = tid & 127;
        float v = 0.f;
        #pragma unroll
        for (int g2 = 0; g2 < 32; g2++) v += racc[g2][rr][k];
        tl[rr][k] = v;
    }
    __syncthreads();
    // ---- final GEMM: out[i][d] = sum_k t[k] * W2t[k][d] + gate*b2[d] ----
    {
        int rr = tid >> 7, d = tid & 127;
        float acc = (gsum[rr] > 0.f) ? b2[d] : 0.f;
        #pragma unroll 8
        for (int k = 0; k < D; k++)
            acc = fmaf(tl[rr][k], W2t[k * D + d], acc);
        out[(i0 + rr) * D + d] = acc;
    }
}

// ---------------------------------------------------------------------------
extern "C" void kernel_launch(void* const* d_in, const int* in_sizes, int n_in,
                              void* d_out, int out_size, void* d_ws, size_t ws_size,
                              hipStream_t stream) {
    (void)in_sizes; (void)n_in; (void)out_size; (void)ws_size;
    const float* h   = (const float*)d_in[0];
    const int*   adj = (const int*)d_in[1];
    const float* pd  = (const float*)d_in[2];
    const float* ut  = (const float*)d_in[3];
    const float* W   = (const float*)d_in[4];
    const float* a   = (const float*)d_in[5];
    const float* W1  = (const float*)d_in[6];
    const float* b1  = (const float*)d_in[7];
    const float* W2  = (const float*)d_in[8];
    const float* b2  = (const float*)d_in[9];
    float* out = (float*)d_out;
    float* ws = (float*)d_ws;

    float* Mt    = ws + OFF_MT;
    float* W2t   = ws + OFF_W2T;
    float* wpd   = ws + OFF_WPD;
    float* wut   = ws + OFF_WUT;
    float* s1    = ws + OFF_S1;
    float* s2    = ws + OFF_S2;
    float* baseb = ws + OFF_BASE;

    prep_kernel<<<197, 256, 0, stream>>>(W, W1, W2, a, h, Mt, W2t, wpd, wut, s1, s2);
    base_kernel<<<128, 256, 0, stream>>>(h, Mt, b1, baseb);
    mega_kernel<<<N / MROWS / 1, 512, 0, stream>>>(baseb, s1, s2, adj, pd, ut,
                                                   wpd, wut, W2t, b2, out);
}